// Round 1
// baseline (393.441 us; speedup 1.0000x reference)
//
#include <hip/hip_runtime.h>

// Problem constants (from setup_inputs): B=16, C=1, H=512, W=640
#define BB 16
#define HH 512
#define WW 640
constexpr int HW = HH * WW;
constexpr float EPS = 0.5f;   // LOSS_EPS

// ---------------- Kernel 1: pattern_proj ----------------
// pat = mean over 3 channels of pattern (1,3,H,W), broadcast over batch.
// x = clip(u - disp0, 0, W-1); lerp gather along W.
__global__ void proj_kernel(const float* __restrict__ disp0,
                            const float* __restrict__ pattern,
                            float* __restrict__ proj,   // d_out + 1
                            float* __restrict__ val)    // d_out (scalar)
{
    int idx = blockIdx.x * 256 + threadIdx.x;
    if (idx == 0) val[0] = 0.0f;          // init accumulator each launch
    if (idx >= BB * HW) return;

    int wp = idx % WW;
    int h  = (idx / WW) % HH;

    float d = disp0[idx];
    float x = (float)wp - d;
    x = fminf(fmaxf(x, 0.0f), (float)(WW - 1));
    int   x0 = (int)x;                    // x >= 0, floor == trunc
    int   x1 = min(x0 + 1, WW - 1);
    float w  = x - (float)x0;

    const float* prow = pattern + h * WW;
    float p0 = (prow[x0] + prow[HW + x0] + prow[2 * HW + x0]) * (1.0f / 3.0f);
    float p1 = (prow[x1] + prow[HW + x1] + prow[2 * HW + x1]) * (1.0f / 3.0f);

    proj[idx] = p0 * (1.0f - w) + p1 * w;
}

// ---------------- Kernel 2: census SAD + mean reduction ----------------
#define TS 16
#define PP 4
#define TL (TS + 2 * PP)   // 24

__global__ void census_kernel(const float* __restrict__ proj,
                              const float* __restrict__ im,
                              float* __restrict__ val)
{
    __shared__ float es_t[TL][TL];
    __shared__ float ta_t[TL][TL];
    __shared__ float wsum[4];

    int bx = blockIdx.x;        // W tiles (40)
    int by = blockIdx.y;        // H tiles (32)
    int b  = blockIdx.z;        // batch (16)
    int tx = threadIdx.x, ty = threadIdx.y;
    int tid = ty * TS + tx;

    const float* pb = proj + (size_t)b * HW;
    const float* ib = im   + (size_t)b * HW;

    int gh0 = by * TS - PP;
    int gw0 = bx * TS - PP;

    // cooperative halo load (24*24 = 576 elems, 256 threads)
    for (int i = tid; i < TL * TL; i += TS * TS) {
        int lh = i / TL, lw = i % TL;
        int gh = gh0 + lh, gw = gw0 + lw;
        bool ok = (gh >= 0) & (gh < HH) & (gw >= 0) & (gw < WW);
        int g = gh * WW + gw;
        es_t[lh][lw] = ok ? pb[g] : 0.0f;
        ta_t[lh][lw] = ok ? ib[g] : 0.0f;
    }
    __syncthreads();

    int h = by * TS + ty;
    int w = bx * TS + tx;

    float es = es_t[ty + PP][tx + PP];
    float ta = ta_t[ty + PP][tx + PP];

    int dhlo = max(-PP, -h),  dhhi = min(PP, HH - 1 - h);
    int dwlo = max(-PP, -w),  dwhi = min(PP, WW - 1 - w);

    int acc = 0;
    for (int dh = dhlo; dh <= dhhi; ++dh) {
        #pragma unroll
        for (int dw = -PP; dw <= PP; ++dw) {
            if (dw < dwlo || dw > dwhi) continue;
            float de = es_t[ty + PP + dh][tx + PP + dw] - es;
            float dt = ta_t[ty + PP + dh][tx + PP + dw] - ta;
            int s1 = (de > EPS) - (de < -EPS);
            int s2 = (dt > EPS) - (dt < -EPS);
            acc += abs(s1 - s2);
        }
    }
    int count = (dhhi - dhlo + 1) * (dwhi - dwlo + 1);
    float pix = (float)acc / (float)count;

    // block reduction: wave64 shuffle, then cross-wave via LDS
    float v = pix;
    #pragma unroll
    for (int off = 32; off > 0; off >>= 1)
        v += __shfl_down(v, off, 64);
    int lane = tid & 63, wid = tid >> 6;
    if (lane == 0) wsum[wid] = v;
    __syncthreads();
    if (tid == 0) {
        float s = wsum[0] + wsum[1] + wsum[2] + wsum[3];
        atomicAdd(val, s * (1.0f / ((float)BB * (float)HW)));
    }
}

extern "C" void kernel_launch(void* const* d_in, const int* in_sizes, int n_in,
                              void* d_out, int out_size, void* d_ws, size_t ws_size,
                              hipStream_t stream) {
    const float* disp0   = (const float*)d_in[0];
    const float* im      = (const float*)d_in[1];
    const float* pattern = (const float*)d_in[2];

    float* out  = (float*)d_out;
    float* proj = out + 1;            // output layout: [val, pattern_proj...]

    int total = BB * HW;
    proj_kernel<<<(total + 255) / 256, 256, 0, stream>>>(disp0, pattern, proj, out);

    dim3 grid(WW / TS, HH / TS, BB);
    dim3 block(TS, TS);
    census_kernel<<<grid, block, 0, stream>>>(proj, im, out);
}

// Round 3
// 173.797 us; speedup vs baseline: 2.2638x; 2.2638x over previous
//
#include <hip/hip_runtime.h>

// B=16, C=1, H=512, W=640
#define BB 16
#define HH 512
#define WW 640
constexpr int HW = HH * WW;
constexpr float BIGF = 1.0e6f;   // OOB fill: sign(BIG-x)=+1 on both sides -> c=0

#define WT 64          // tile width
#define HT 32          // tile height
#define RP 8           // rows per thread (4 row-groups of 64 threads)
#define PAD 4          // census radius
#define LW (WT + 2*PAD)   // 72
#define LH (HT + 2*PAD)   // 40

__global__ __launch_bounds__(256)
void fused_kernel(const float* __restrict__ disp0,
                  const float* __restrict__ im,
                  const float* __restrict__ pattern,
                  float* __restrict__ out)   // [val, proj...]
{
    __shared__ float es_t[LH * LW];
    __shared__ float ta_t[LH * LW];
    __shared__ float wsum[4];

    const int bx = blockIdx.x, by = blockIdx.y, b = blockIdx.z;
    const int tx = threadIdx.x;     // 0..63 (column)
    const int rg = threadIdx.y;     // 0..3  (row group == wave)
    const int tid = rg * 64 + tx;

    const float* db = disp0 + (size_t)b * HW;
    const float* ib = im    + (size_t)b * HW;
    float* proj = out + 1 + (size_t)b * HW;

    const int gh0 = by * HT - PAD;
    const int gw0 = bx * WT - PAD;

    // ---- staging: fused projection (gather+lerp) + im, halo filled with BIGF
    #pragma unroll
    for (int it = 0; it < (LH * LW + 255) / 256; ++it) {
        int i = tid + it * 256;
        if (i < LH * LW) {
            int lh = i / LW;
            int lw = i - lh * LW;
            int gh = gh0 + lh, gw = gw0 + lw;
            float ev = BIGF, tv = BIGF;
            if ((gh >= 0) & (gh < HH) & (gw >= 0) & (gw < WW)) {
                int g = gh * WW + gw;
                float d = db[g];
                float x = fminf(fmaxf((float)gw - d, 0.0f), (float)(WW - 1));
                int   x0 = (int)x;
                int   x1 = min(x0 + 1, WW - 1);
                float w  = x - (float)x0;
                const float* prow = pattern + gh * WW;
                float p0 = (prow[x0] + prow[HW + x0] + prow[2*HW + x0]) * (1.0f/3.0f);
                float p1 = (prow[x1] + prow[HW + x1] + prow[2*HW + x1]) * (1.0f/3.0f);
                ev = p0 * (1.0f - w) + p1 * w;
                tv = ib[g];
                if ((lh >= PAD) & (lh < PAD + HT) & (lw >= PAD) & (lw < PAD + WT))
                    proj[g] = ev;          // each interior pixel written exactly once
            }
            es_t[i] = ev;
            ta_t[i] = tv;
        }
    }
    __syncthreads();

    // ---- census: sliding 16-row window over 8 center rows per thread
    float ec[RP], tc[RP], acc[RP];
    #pragma unroll
    for (int p = 0; p < RP; ++p) {
        int lr = rg * RP + p + PAD;
        ec[p]  = es_t[lr * LW + tx + PAD];
        tc[p]  = ta_t[lr * LW + tx + PAD];
        acc[p] = 0.0f;
    }

    for (int wr = 0; wr < RP + 2 * PAD; ++wr) {   // 16 window rows
        int lr = rg * RP + wr;
        float e[9], t[9];
        #pragma unroll
        for (int j = 0; j < 9; ++j) {
            e[j] = es_t[lr * LW + tx + j];
            t[j] = ta_t[lr * LW + tx + j];
        }
        #pragma unroll
        for (int p = 0; p < RP; ++p) {
            if (p >= wr - 2 * PAD && p <= wr) {   // dh = wr-4-p in [-4,4]
                #pragma unroll
                for (int j = 0; j < 9; ++j) {
                    // sign_eps(d) == rintf(clamp(d,-1,1)) exactly (eps=0.5)
                    float s1 = rintf(fminf(fmaxf(e[j] - ec[p], -1.0f), 1.0f));
                    float s2 = rintf(fminf(fmaxf(t[j] - tc[p], -1.0f), 1.0f));
                    acc[p] += fabsf(s1 - s2);
                }
            }
        }
    }

    // ---- per-pixel normalize by valid count, block reduce, one atomic
    const int w  = bx * WT + tx;
    const int cw = min(PAD, WW - 1 - w) + min(PAD, w) + 1;
    float tsum = 0.0f;
    #pragma unroll
    for (int p = 0; p < RP; ++p) {
        int h  = by * HT + rg * RP + p;
        int ch = min(PAD, HH - 1 - h) + min(PAD, h) + 1;
        tsum += acc[p] / (float)(ch * cw);
    }
    #pragma unroll
    for (int off = 32; off > 0; off >>= 1)
        tsum += __shfl_down(tsum, off, 64);
    if (tx == 0) wsum[rg] = tsum;
    __syncthreads();
    if (tid == 0) {
        float s = (wsum[0] + wsum[1] + wsum[2] + wsum[3]) * (1.0f / ((float)BB * (float)HW));
        atomicAdd(out, s);
    }
}

extern "C" void kernel_launch(void* const* d_in, const int* in_sizes, int n_in,
                              void* d_out, int out_size, void* d_ws, size_t ws_size,
                              hipStream_t stream) {
    const float* disp0   = (const float*)d_in[0];
    const float* im      = (const float*)d_in[1];
    const float* pattern = (const float*)d_in[2];
    float* out = (float*)d_out;

    hipMemsetAsync(d_out, 0, sizeof(float), stream);   // zero the scalar accumulator

    dim3 grid(WW / WT, HH / HT, BB);   // 10, 16, 16
    dim3 block(64, 4);
    fused_kernel<<<grid, block, 0, stream>>>(disp0, im, pattern, out);
}

// Round 5
// 158.865 us; speedup vs baseline: 2.4766x; 1.0940x over previous
//
#include <hip/hip_runtime.h>

// B=16, C=1, H=512, W=640
#define BB 16
#define HH 512
#define WW 640
constexpr int HW = HH * WW;

#define WT 64
#define HT 32
#define PAD 4
#define LW (WT + 2*PAD)      // 72 (left+right halo)
#define LH (HT + PAD)        // 36 (bottom halo only; pair-symmetry needs no top)
#define GX (WW / WT)         // 10
#define GY (HH / HT)         // 16
#define NBLK (GX * GY * BB)  // 2560

typedef _Float16 h2 __attribute__((ext_vector_type(2)));

constexpr float HALO = 30000.0f;   // finite in f16; sign(HALO-x)=+1 both sides -> c=0

__device__ __forceinline__ float fast_rcp(float x) {
#if __has_builtin(__builtin_amdgcn_rcpf)
    return __builtin_amdgcn_rcpf(x);
#else
    return 1.0f / x;
#endif
}

__device__ __forceinline__ _Float16 habs(_Float16 x) {
    union { _Float16 h; unsigned short u; } v;
    v.h = x; v.u &= 0x7fffu;
    return v.h;
}

// Forward-pair census sum for this thread's 8 center rows.
// Pairs: dh in 1..4 with dw -4..4, plus dh==0 with dw 1..4 (40 taps).
// INTERIOR: all pair weights are 2/81 (applied by caller). EDGE: per-tap fma weight.
template<bool EDGE>
__device__ __forceinline__ float census_sum(const h2* sm, int tx, int rg,
                                            int bx, int by)
{
    const h2 K2   = { (_Float16)1536.0f, (_Float16)1536.0f };
    const h2 ONE2 = { (_Float16)1.0f,  (_Float16)1.0f };
    const h2 NEG2 = { (_Float16)-1.0f, (_Float16)-1.0f };

    float invcw[9];
    if constexpr (EDGE) {
        int w0 = bx * WT + tx;
        #pragma unroll
        for (int j = 0; j < 9; ++j) {
            int c  = w0 + j - 4;                       // may be OOB: cw>=1 there
            int cw = min(4, WW - 1 - c) + min(4, c) + 1;
            invcw[j] = fast_rcp((float)cw);
        }
    }

    float tsum = 0.0f;
    #pragma unroll 1
    for (int p = 0; p < 8; ++p) {
        const int lr = rg * 8 + p;                     // tile row 0..31
        const h2* base = sm + lr * LW + tx;            // tap (dh,j) at base[dh*LW+j]
        const h2 ct = base[PAD];                       // center (es,ta) packed

        float invch[5], wp;
        float facc = 0.0f;
        _Float16 hacc = (_Float16)0.0f;
        if constexpr (EDGE) {
            int r0 = by * HT + lr;
            #pragma unroll
            for (int d = 0; d < 5; ++d) {
                int r  = r0 + d;                       // may be OOB: ch>=1
                int ch = min(4, HH - 1 - r) + min(4, r) + 1;
                invch[d] = fast_rcp((float)ch);
            }
            wp = invch[0] * invcw[4];
        }

        auto tap = [&](int dh, int j) {
            h2 d2 = base[dh * LW + j] - ct;            // (de, dt) packed
            d2 = __builtin_elementwise_max(d2, NEG2);
            d2 = __builtin_elementwise_min(d2, ONE2);
            d2 = d2 + K2;                              // RNE to integer
            d2 = d2 - K2;                              // (s1, s2) in {-1,0,1}
            _Float16 diff = d2.x - d2.y;
            if constexpr (EDGE) {
                float c  = fabsf((float)diff);
                float wt = fmaf(invch[dh], invcw[j], wp);  // 1/cnt_q + 1/cnt_p
                facc = fmaf(c, wt, facc);
            } else {
                hacc = hacc + habs(diff);
            }
        };

        #pragma unroll
        for (int j = 5; j <= 8; ++j) tap(0, j);
        #pragma unroll
        for (int dh = 1; dh <= 4; ++dh) {
            #pragma unroll
            for (int j = 0; j <= 8; ++j) tap(dh, j);
        }

        tsum += EDGE ? facc : (float)hacc;
    }
    return tsum;
}

__global__ __launch_bounds__(256)
void fused_kernel(const float* __restrict__ disp0,
                  const float* __restrict__ im,
                  const float* __restrict__ pattern,
                  float* __restrict__ out,       // [val, proj...]
                  float* __restrict__ partial)   // d_ws, NBLK floats
{
    __shared__ h2 sm[LH * LW];
    __shared__ float wsum[4];

    const int bx = blockIdx.x, by = blockIdx.y, b = blockIdx.z;
    const int tx = threadIdx.x;      // 0..63
    const int rg = threadIdx.y;      // 0..3
    const int tid = rg * 64 + tx;

    const float* db = disp0 + (size_t)b * HW;
    const float* ib = im    + (size_t)b * HW;
    float* proj = out + 1 + (size_t)b * HW;

    const int gh0 = by * HT;           // LDS row 0 == tile top (no top halo)
    const int gw0 = bx * WT - PAD;     // LDS col 0

    // ---- staging: fused projection + im -> packed f16x2 LDS, proj written f32
    #pragma unroll
    for (int it = 0; it < (LH * LW + 255) / 256; ++it) {
        int i = tid + it * 256;
        if (i < LH * LW) {
            int lh = i / LW;
            int lw = i - lh * LW;
            int gh = gh0 + lh, gw = gw0 + lw;
            float ev = HALO, tv = HALO;
            if ((gh < HH) & (gw >= 0) & (gw < WW)) {
                int g = gh * WW + gw;
                float d = db[g];
                float x = fminf(fmaxf((float)gw - d, 0.0f), (float)(WW - 1));
                int   x0 = (int)x;
                int   x1 = min(x0 + 1, WW - 1);
                float w  = x - (float)x0;
                const float* prow = pattern + gh * WW;
                float p0 = (prow[x0] + prow[HW + x0] + prow[2*HW + x0]) * (1.0f/3.0f);
                float p1 = (prow[x1] + prow[HW + x1] + prow[2*HW + x1]) * (1.0f/3.0f);
                ev = p0 * (1.0f - w) + p1 * w;
                tv = ib[g];
                if ((lh < HT) & (lw >= PAD) & (lw < PAD + WT))
                    proj[g] = ev;      // each image pixel written exactly once
            }
            h2 pk = { (_Float16)ev, (_Float16)tv };
            sm[i] = pk;
        }
    }
    __syncthreads();

    // ---- census (pair-symmetric, packed f16)
    float tsum;
    if ((bx >= 1) & (bx <= GX - 2) & (by >= 1) & (by <= GY - 2)) {
        tsum = census_sum<false>(sm, tx, rg, bx, by) * (2.0f / 81.0f);
    } else {
        tsum = census_sum<true>(sm, tx, rg, bx, by);
    }

    // ---- block reduce -> one partial per block (no atomics)
    #pragma unroll
    for (int off = 32; off > 0; off >>= 1)
        tsum += __shfl_down(tsum, off, 64);
    if (tx == 0) wsum[rg] = tsum;
    __syncthreads();
    if (tid == 0)
        partial[(b * GY + by) * GX + bx] = wsum[0] + wsum[1] + wsum[2] + wsum[3];
}

__global__ __launch_bounds__(256)
void reduce_kernel(const float* __restrict__ partial, float* __restrict__ out)
{
    __shared__ float wsum[4];
    int t = threadIdx.x;
    float s = 0.0f;
    #pragma unroll
    for (int i = 0; i < NBLK / 256; ++i) s += partial[t + i * 256];
    #pragma unroll
    for (int off = 32; off > 0; off >>= 1)
        s += __shfl_down(s, off, 64);
    if ((t & 63) == 0) wsum[t >> 6] = s;
    __syncthreads();
    if (t == 0)
        out[0] = (wsum[0] + wsum[1] + wsum[2] + wsum[3]) * (1.0f / ((float)BB * (float)HW));
}

extern "C" void kernel_launch(void* const* d_in, const int* in_sizes, int n_in,
                              void* d_out, int out_size, void* d_ws, size_t ws_size,
                              hipStream_t stream) {
    const float* disp0   = (const float*)d_in[0];
    const float* im      = (const float*)d_in[1];
    const float* pattern = (const float*)d_in[2];
    float* out = (float*)d_out;
    float* partial = (float*)d_ws;   // NBLK floats = 10 KB

    dim3 grid(GX, GY, BB);           // 10, 16, 16
    dim3 block(64, 4);
    fused_kernel<<<grid, block, 0, stream>>>(disp0, im, pattern, out, partial);
    reduce_kernel<<<1, 256, 0, stream>>>(partial, out);
}